// Round 7
// baseline (88.607 us; speedup 1.0000x reference)
//
#include <hip/hip_runtime.h>
#include <math.h>

// Constants: MASS=1.0, CHARGE=0.5, ALPHA=0.1, BETA=0.05, ETA=(+1,-1,-1,-1)
// f64 replica of the JAX reference. jnp.linalg.pinv default rcond
//   = 10*max(M,N)*eps_f32 = 4.76837158203125e-6 (verified round 4).
// Round 7: single dispatch with IN-BLOCK LDS compaction. Unsafe lanes
// (min|lambda| not provably > 6*cutoff; ~2e-3 of particles) stash {A,f,d}
// in LDS; after a barrier, lanes 0..n-1 of wave 0 run the Jacobi+truncated
// pinv. No workspace, no memset, no second kernel. Jacobi cut 8->5 sweeps
// (4x4 cyclic Jacobi off-diag < 1e-15*sigma by sweep 4-5).

#define SIX_RCOND 2.86102294921875e-5   // 6 * rcond
#define RCOND     4.76837158203125e-6
#define MAXSLOW   8                     // Poisson(0.5) per block; P(>8)~1e-9

__device__ __forceinline__ void model_terms(
    const double* sW, const double* sV,
    const double x[4], const double u[4],
    double A[4], double f[4], double d[4])
{
    const double eta[4] = {1.0, -1.0, -1.0, -1.0};
    const double CHG = 0.5, ALPHA = 0.1, BETA = 0.05;
    double G[4][4];
    #pragma unroll
    for (int j = 0; j < 4; ++j) {
        double t = 0.0, s = 0.0;
        #pragma unroll
        for (int k = 0; k < 4; ++k) { t += sW[j*4+k]*x[k]; s += sV[j*4+k]*x[k]; }
        double th = tanh(t);
        A[j] = th + s;
        double dth = 1.0 - th * th;
        #pragma unroll
        for (int k = 0; k < 4; ++k) G[j][k] = dth * sW[j*4+k] + sV[j*4+k];
    }
    double S = 0.0;
    #pragma unroll
    for (int k = 0; k < 4; ++k) S += u[k] * A[k];
    double P[4], R[4], Q[4];
    #pragma unroll
    for (int j = 0; j < 4; ++j) {
        double p = 0.0, r = 0.0, q = 0.0;
        #pragma unroll
        for (int k = 0; k < 4; ++k) {
            p += G[k][j] * u[k];
            r += G[j][k] * u[k];
            q += G[k][j] * (CHG * eta[k]) * u[k];
        }
        P[j] = p; R[j] = r; Q[j] = q;
    }
    double T = 0.0;
    #pragma unroll
    for (int j = 0; j < 4; ++j) T += u[j] * R[j];
    #pragma unroll
    for (int j = 0; j < 4; ++j) {
        f[j] = -2.0 * ALPHA * x[j] * u[j] * u[j]
             + Q[j]
             + 2.0 * BETA * S * P[j]
             - (CHG * eta[j] + 2.0 * BETA * S) * R[j]
             - 2.0 * BETA * A[j] * T;
        d[j] = eta[j] + 2.0 * ALPHA * x[j] * x[j];
    }
}

__device__ __forceinline__ void sm_solve(
    const double d[4], const double A[4], const double f[4], double acc[4])
{
    const double C2 = 0.1;
    double b[4], fd[4], den = 1.0, w = 0.0;
    #pragma unroll
    for (int j = 0; j < 4; ++j) {
        double inv = 1.0 / d[j];
        b[j]  = A[j] * inv;
        fd[j] = f[j] * inv;
        den  += C2 * A[j] * b[j];
        w    += b[j] * f[j];
    }
    double scale = C2 * w / den;
    #pragma unroll
    for (int j = 0; j < 4; ++j) acc[j] = fd[j] - b[j] * scale;
}

__device__ void jacobi_pinv_solve(
    const double d[4], const double A[4], const double f[4], double acc[4])
{
    const double C2 = 0.1;
    double M[4][4], Vm[4][4];
    #pragma unroll
    for (int r = 0; r < 4; ++r) {
        #pragma unroll
        for (int c = 0; c < 4; ++c) {
            M[r][c] = C2 * A[r] * A[c];
            Vm[r][c] = (r == c) ? 1.0 : 0.0;
        }
        M[r][r] += d[r];
    }
    for (int sweep = 0; sweep < 5; ++sweep) {
        #pragma unroll
        for (int p = 0; p < 3; ++p) {
            #pragma unroll
            for (int q2 = p + 1; q2 < 4; ++q2) {
                double apq = M[p][q2];
                if (fabs(apq) < 1e-280) continue;
                double app = M[p][p], aqq = M[q2][q2];
                double tau = (aqq - app) / (2.0 * apq);
                double tt = ((tau >= 0.0) ? 1.0 : -1.0) /
                            (fabs(tau) + sqrt(1.0 + tau * tau));
                double c = 1.0 / sqrt(1.0 + tt * tt);
                double s = tt * c;
                #pragma unroll
                for (int k = 0; k < 4; ++k) {
                    double mkp = M[k][p], mkq = M[k][q2];
                    M[k][p]  = c * mkp - s * mkq;
                    M[k][q2] = s * mkp + c * mkq;
                }
                #pragma unroll
                for (int k = 0; k < 4; ++k) {
                    double mpk = M[p][k], mqk = M[q2][k];
                    M[p][k]  = c * mpk - s * mqk;
                    M[q2][k] = s * mpk + c * mqk;
                }
                #pragma unroll
                for (int k = 0; k < 4; ++k) {
                    double vkp = Vm[k][p], vkq = Vm[k][q2];
                    Vm[k][p]  = c * vkp - s * vkq;
                    Vm[k][q2] = s * vkp + c * vkq;
                }
            }
        }
    }
    double lam[4], sigmax = 0.0;
    #pragma unroll
    for (int k = 0; k < 4; ++k) {
        lam[k] = M[k][k];
        double a = fabs(lam[k]);
        sigmax = (a > sigmax) ? a : sigmax;
    }
    double cutoff = RCOND * sigmax;
    #pragma unroll
    for (int j = 0; j < 4; ++j) acc[j] = 0.0;
    #pragma unroll
    for (int e = 0; e < 4; ++e) {
        if (fabs(lam[e]) > cutoff) {
            double coef = 0.0;
            #pragma unroll
            for (int k = 0; k < 4; ++k) coef += Vm[k][e] * f[k];
            coef /= lam[e];
            #pragma unroll
            for (int j = 0; j < 4; ++j) acc[j] += coef * Vm[j][e];
        }
    }
}

__global__ __launch_bounds__(256) void rel_particle_kernel(
    const float* __restrict__ y, const float* __restrict__ W,
    const float* __restrict__ V, float* __restrict__ out, int B)
{
    __shared__ double sW[16], sV[16];
    __shared__ double stash[MAXSLOW][12];
    __shared__ int    sidx[MAXSLOW];
    __shared__ int    scnt;

    int tid = threadIdx.x;
    if (tid < 16)      sW[tid]      = (double)W[tid];
    else if (tid < 32) sV[tid - 16] = (double)V[tid - 16];
    if (tid == 32) scnt = 0;
    __syncthreads();

    int i = blockIdx.x * blockDim.x + tid;
    if (i < B) {
        const float4* y4 = (const float4*)y;
        float4 xv = y4[2 * i];
        float4 uv = y4[2 * i + 1];
        double x[4] = {xv.x, xv.y, xv.z, xv.w};
        double u[4] = {uv.x, uv.y, uv.z, uv.w};

        double A[4], f[4], d[4];
        model_terms(sW, sV, x, u, A, f, d);

        const double C2 = 0.1;
        double mind = 1e300;
        #pragma unroll
        for (int j = 0; j < 4; ++j) {
            double a = fabs(d[j]);
            mind = (a < mind) ? a : mind;
        }
        // det(J) = prod(d) + C2 * sum_i A_i^2 * prod_{j!=i} d_j
        double p01 = d[0] * d[1], p23 = d[2] * d[3];
        double det = p01 * p23
            + C2 * (A[0]*A[0]*(d[1]*p23) + A[1]*A[1]*(d[0]*p23) +
                    A[2]*A[2]*(p01*d[3]) + A[3]*A[3]*(p01*d[2]));
        // sigma_max^2 upper bound: min(Frobenius^2, (max row sum)^2)
        double sumA2 = 0.0, sumA4 = 0.0, F2 = 0.0;
        #pragma unroll
        for (int j = 0; j < 4; ++j) {
            double Aj2 = A[j] * A[j];
            sumA2 += Aj2; sumA4 += Aj2 * Aj2;
            double Jjj = d[j] + C2 * Aj2;
            F2 += Jjj * Jjj;
        }
        F2 += C2 * C2 * (sumA2 * sumA2 - sumA4);
        double rowmax = 0.0;
        #pragma unroll
        for (int r = 0; r < 4; ++r) {
            double rs = 0.0;
            #pragma unroll
            for (int c = 0; c < 4; ++c) {
                double Jrc = C2 * A[r] * A[c] + ((r == c) ? d[r] : 0.0);
                rs += fabs(Jrc);
            }
            rowmax = (rs > rowmax) ? rs : rowmax;
        }
        double sig_hi2 = rowmax * rowmax;
        sig_hi2 = (F2 < sig_hi2) ? F2 : sig_hi2;
        // |det| > 6*rcond*sig_hi^4  =>  min|lambda| > 6*cutoff => pinv == inv
        bool safe = (fabs(det) > SIX_RCOND * sig_hi2 * sig_hi2) && (mind > 1e-3);

        if (safe) {
            double acc[4];
            sm_solve(d, A, f, acc);
            float4 res;
            res.x = (float)acc[0]; res.y = (float)acc[1];
            res.z = (float)acc[2]; res.w = (float)acc[3];
            ((float4*)out)[i] = res;
        } else {
            int k = atomicAdd(&scnt, 1);
            if (k < MAXSLOW) {
                sidx[k] = i;
                #pragma unroll
                for (int j = 0; j < 4; ++j) {
                    stash[k][j]     = A[j];
                    stash[k][4 + j] = f[j];
                    stash[k][8 + j] = d[j];
                }
            } else {
                // statistically unreachable overflow: best-effort SM
                double acc[4];
                sm_solve(d, A, f, acc);
                float4 res;
                res.x = (float)acc[0]; res.y = (float)acc[1];
                res.z = (float)acc[2]; res.w = (float)acc[3];
                ((float4*)out)[i] = res;
            }
        }
    }
    __syncthreads();

    int n = scnt;
    if (n > MAXSLOW) n = MAXSLOW;
    if (tid < n) {
        double A[4], f[4], d[4];
        #pragma unroll
        for (int j = 0; j < 4; ++j) {
            A[j] = stash[tid][j];
            f[j] = stash[tid][4 + j];
            d[j] = stash[tid][8 + j];
        }
        double acc[4];
        jacobi_pinv_solve(d, A, f, acc);
        float4 res;
        res.x = (float)acc[0]; res.y = (float)acc[1];
        res.z = (float)acc[2]; res.w = (float)acc[3];
        ((float4*)out)[sidx[tid]] = res;
    }
}

extern "C" void kernel_launch(void* const* d_in, const int* in_sizes, int n_in,
                              void* d_out, int out_size, void* d_ws, size_t ws_size,
                              hipStream_t stream) {
    const float* y = (const float*)d_in[0];
    const float* W = (const float*)d_in[1];
    const float* V = (const float*)d_in[2];
    float* out = (float*)d_out;
    int B = in_sizes[0] / 8;
    int block = 256;
    int grid = (B + block - 1) / block;
    rel_particle_kernel<<<grid, block, 0, stream>>>(y, W, V, out, B);
}

// Round 8
// 88.556 us; speedup vs baseline: 1.0006x; 1.0006x over previous
//
#include <hip/hip_runtime.h>
#include <math.h>

// Constants: MASS=1.0, CHARGE=0.5, ALPHA=0.1, BETA=0.05, ETA=(+1,-1,-1,-1)
// f64-reference-equivalent kernel. jnp.linalg.pinv default rcond
//   = 10*max(M,N)*eps_f32 = 4.76837158203125e-6 (verified round 4).
// Round 8: fast path fully in f32 (latency-bound f64 tanh/div chains were
// the cost — VALUBusy 15.7% at 4 waves/SIMD). Classification threshold
// inflated 2.8x (8e-5 vs exact 2.86e-5) so every particle whose f64
// min|lambda| could be near the pinv cutoff is routed to the in-block f64
// tail, which recomputes from x,u in full f64 (bit-identical to round 4).
// Safe-path f32 error <= ~eps32 * kappa (kappa < 1.3e4) ~ 0.1% relative.

#define RCOND        4.76837158203125e-6
#define SAFE_DET_F32 8.0e-5f            // inflated vs exact 2.861e-5
#define MAXSLOW      16                 // Poisson(~1.5)/block; P(>16)~1e-13

// ---------------- f64 exact path (tail + overflow fallback) ---------------
__device__ void model_terms_f64(
    const double* sW, const double* sV,
    const double x[4], const double u[4],
    double A[4], double f[4], double d[4])
{
    const double eta[4] = {1.0, -1.0, -1.0, -1.0};
    const double CHG = 0.5, ALPHA = 0.1, BETA = 0.05;
    double G[4][4];
    #pragma unroll
    for (int j = 0; j < 4; ++j) {
        double t = 0.0, s = 0.0;
        #pragma unroll
        for (int k = 0; k < 4; ++k) { t += sW[j*4+k]*x[k]; s += sV[j*4+k]*x[k]; }
        double th = tanh(t);
        A[j] = th + s;
        double dth = 1.0 - th * th;
        #pragma unroll
        for (int k = 0; k < 4; ++k) G[j][k] = dth * sW[j*4+k] + sV[j*4+k];
    }
    double S = 0.0;
    #pragma unroll
    for (int k = 0; k < 4; ++k) S += u[k] * A[k];
    double P[4], R[4], Q[4];
    #pragma unroll
    for (int j = 0; j < 4; ++j) {
        double p = 0.0, r = 0.0, q = 0.0;
        #pragma unroll
        for (int k = 0; k < 4; ++k) {
            p += G[k][j] * u[k];
            r += G[j][k] * u[k];
            q += G[k][j] * (CHG * eta[k]) * u[k];
        }
        P[j] = p; R[j] = r; Q[j] = q;
    }
    double T = 0.0;
    #pragma unroll
    for (int j = 0; j < 4; ++j) T += u[j] * R[j];
    #pragma unroll
    for (int j = 0; j < 4; ++j) {
        f[j] = -2.0 * ALPHA * x[j] * u[j] * u[j]
             + Q[j]
             + 2.0 * BETA * S * P[j]
             - (CHG * eta[j] + 2.0 * BETA * S) * R[j]
             - 2.0 * BETA * A[j] * T;
        d[j] = eta[j] + 2.0 * ALPHA * x[j] * x[j];
    }
}

__device__ void jacobi_pinv_solve(
    const double d[4], const double A[4], const double f[4], double acc[4])
{
    const double C2 = 0.1;
    double M[4][4], Vm[4][4];
    #pragma unroll
    for (int r = 0; r < 4; ++r) {
        #pragma unroll
        for (int c = 0; c < 4; ++c) {
            M[r][c] = C2 * A[r] * A[c];
            Vm[r][c] = (r == c) ? 1.0 : 0.0;
        }
        M[r][r] += d[r];
    }
    for (int sweep = 0; sweep < 5; ++sweep) {
        #pragma unroll
        for (int p = 0; p < 3; ++p) {
            #pragma unroll
            for (int q2 = p + 1; q2 < 4; ++q2) {
                double apq = M[p][q2];
                if (fabs(apq) < 1e-280) continue;
                double app = M[p][p], aqq = M[q2][q2];
                double tau = (aqq - app) / (2.0 * apq);
                double tt = ((tau >= 0.0) ? 1.0 : -1.0) /
                            (fabs(tau) + sqrt(1.0 + tau * tau));
                double c = 1.0 / sqrt(1.0 + tt * tt);
                double s = tt * c;
                #pragma unroll
                for (int k = 0; k < 4; ++k) {
                    double mkp = M[k][p], mkq = M[k][q2];
                    M[k][p]  = c * mkp - s * mkq;
                    M[k][q2] = s * mkp + c * mkq;
                }
                #pragma unroll
                for (int k = 0; k < 4; ++k) {
                    double mpk = M[p][k], mqk = M[q2][k];
                    M[p][k]  = c * mpk - s * mqk;
                    M[q2][k] = s * mpk + c * mqk;
                }
                #pragma unroll
                for (int k = 0; k < 4; ++k) {
                    double vkp = Vm[k][p], vkq = Vm[k][q2];
                    Vm[k][p]  = c * vkp - s * vkq;
                    Vm[k][q2] = s * vkp + c * vkq;
                }
            }
        }
    }
    double lam[4], sigmax = 0.0;
    #pragma unroll
    for (int k = 0; k < 4; ++k) {
        lam[k] = M[k][k];
        double a = fabs(lam[k]);
        sigmax = (a > sigmax) ? a : sigmax;
    }
    double cutoff = RCOND * sigmax;
    #pragma unroll
    for (int j = 0; j < 4; ++j) acc[j] = 0.0;
    #pragma unroll
    for (int e = 0; e < 4; ++e) {
        if (fabs(lam[e]) > cutoff) {
            double coef = 0.0;
            #pragma unroll
            for (int k = 0; k < 4; ++k) coef += Vm[k][e] * f[k];
            coef /= lam[e];
            #pragma unroll
            for (int j = 0; j < 4; ++j) acc[j] += coef * Vm[j][e];
        }
    }
}

// --------------------------------- kernel ---------------------------------
__global__ __launch_bounds__(256) void rel_particle_kernel(
    const float* __restrict__ y, const float* __restrict__ W,
    const float* __restrict__ V, float* __restrict__ out, int B)
{
    __shared__ float  sWf[16], sVf[16];
    __shared__ double sWd[16], sVd[16];
    __shared__ int    sidx[MAXSLOW];
    __shared__ int    scnt;

    int tid = threadIdx.x;
    if (tid < 16) {
        float w = W[tid];
        sWf[tid] = w; sWd[tid] = (double)w;
    } else if (tid < 32) {
        float v = V[tid - 16];
        sVf[tid - 16] = v; sVd[tid - 16] = (double)v;
    }
    if (tid == 32) scnt = 0;
    __syncthreads();

    int i = blockIdx.x * blockDim.x + tid;
    float4 xv, uv;
    if (i < B) {
        const float4* y4 = (const float4*)y;
        xv = y4[2 * i];
        uv = y4[2 * i + 1];
        float x[4] = {xv.x, xv.y, xv.z, xv.w};
        float u[4] = {uv.x, uv.y, uv.z, uv.w};
        const float eta[4] = {1.f, -1.f, -1.f, -1.f};
        const float CHG = 0.5f, ALPHA = 0.1f, BETA = 0.05f, C2 = 0.1f;

        // ---- f32 model terms ----
        float A[4], G[4][4];
        #pragma unroll
        for (int j = 0; j < 4; ++j) {
            float t = 0.f, s = 0.f;
            #pragma unroll
            for (int k = 0; k < 4; ++k) {
                t += sWf[j*4+k] * x[k];
                s += sVf[j*4+k] * x[k];
            }
            float th = tanhf(t);
            A[j] = th + s;
            float dth = 1.f - th * th;
            #pragma unroll
            for (int k = 0; k < 4; ++k) G[j][k] = dth * sWf[j*4+k] + sVf[j*4+k];
        }
        float S = 0.f;
        #pragma unroll
        for (int k = 0; k < 4; ++k) S += u[k] * A[k];
        float P[4], R[4], Q[4];
        #pragma unroll
        for (int j = 0; j < 4; ++j) {
            float p = 0.f, r = 0.f, q = 0.f;
            #pragma unroll
            for (int k = 0; k < 4; ++k) {
                p += G[k][j] * u[k];
                r += G[j][k] * u[k];
                q += G[k][j] * (CHG * eta[k]) * u[k];
            }
            P[j] = p; R[j] = r; Q[j] = q;
        }
        float T = 0.f;
        #pragma unroll
        for (int j = 0; j < 4; ++j) T += u[j] * R[j];
        float f[4], d[4];
        float mind = 1e30f;
        #pragma unroll
        for (int j = 0; j < 4; ++j) {
            f[j] = -2.f * ALPHA * x[j] * u[j] * u[j]
                 + Q[j]
                 + 2.f * BETA * S * P[j]
                 - (CHG * eta[j] + 2.f * BETA * S) * R[j]
                 - 2.f * BETA * A[j] * T;
            d[j] = eta[j] + 2.f * ALPHA * x[j] * x[j];
            float a = fabsf(d[j]);
            mind = (a < mind) ? a : mind;
        }

        // ---- f32 classification with inflated margins ----
        float p01 = d[0]*d[1], p23 = d[2]*d[3];
        float det = p01 * p23
            + C2 * (A[0]*A[0]*(d[1]*p23) + A[1]*A[1]*(d[0]*p23) +
                    A[2]*A[2]*(p01*d[3]) + A[3]*A[3]*(p01*d[2]));
        float sumA2 = 0.f, sumA4 = 0.f, F2 = 0.f;
        #pragma unroll
        for (int j = 0; j < 4; ++j) {
            float Aj2 = A[j]*A[j];
            sumA2 += Aj2; sumA4 += Aj2*Aj2;
            float Jjj = d[j] + C2*Aj2;
            F2 += Jjj*Jjj;
        }
        F2 += C2*C2*(sumA2*sumA2 - sumA4);
        float rowmax = 0.f;
        #pragma unroll
        for (int r = 0; r < 4; ++r) {
            float rs = 0.f;
            #pragma unroll
            for (int c = 0; c < 4; ++c) {
                float Jrc = C2*A[r]*A[c] + ((r == c) ? d[r] : 0.f);
                rs += fabsf(Jrc);
            }
            rowmax = (rs > rowmax) ? rs : rowmax;
        }
        float sig2 = rowmax*rowmax;
        sig2 = (F2 < sig2) ? F2 : sig2;
        bool safe = (fabsf(det) > SAFE_DET_F32 * sig2 * sig2) && (mind > 1e-3f);

        if (safe) {
            // f32 Sherman-Morrison (kappa < ~1.3e4 guaranteed by margin)
            float b[4], fd[4], den = 1.f, w = 0.f;
            #pragma unroll
            for (int j = 0; j < 4; ++j) {
                float inv = 1.f / d[j];
                b[j]  = A[j] * inv;
                fd[j] = f[j] * inv;
                den  += C2 * A[j] * b[j];
                w    += b[j] * f[j];
            }
            float scale = C2 * w / den;
            float4 res;
            res.x = fd[0] - b[0]*scale;
            res.y = fd[1] - b[1]*scale;
            res.z = fd[2] - b[2]*scale;
            res.w = fd[3] - b[3]*scale;
            ((float4*)out)[i] = res;
        } else {
            int k = atomicAdd(&scnt, 1);
            if (k < MAXSLOW) {
                sidx[k] = i;      // exact f64 recompute in the tail
            } else {
                // statistically unreachable: inline exact f64 path
                double xd[4] = {xv.x, xv.y, xv.z, xv.w};
                double ud[4] = {uv.x, uv.y, uv.z, uv.w};
                double Ad[4], fdd[4], dd[4], acc[4];
                model_terms_f64(sWd, sVd, xd, ud, Ad, fdd, dd);
                jacobi_pinv_solve(dd, Ad, fdd, acc);
                float4 res;
                res.x = (float)acc[0]; res.y = (float)acc[1];
                res.z = (float)acc[2]; res.w = (float)acc[3];
                ((float4*)out)[i] = res;
            }
        }
    }
    __syncthreads();

    int n = scnt;
    if (n > MAXSLOW) n = MAXSLOW;
    if (tid < n) {
        int pi = sidx[tid];
        const float4* y4 = (const float4*)y;
        float4 xw = y4[2 * pi];
        float4 uw = y4[2 * pi + 1];
        double xd[4] = {xw.x, xw.y, xw.z, xw.w};
        double ud[4] = {uw.x, uw.y, uw.z, uw.w};
        double Ad[4], fdd[4], dd[4], acc[4];
        model_terms_f64(sWd, sVd, xd, ud, Ad, fdd, dd);
        jacobi_pinv_solve(dd, Ad, fdd, acc);
        float4 res;
        res.x = (float)acc[0]; res.y = (float)acc[1];
        res.z = (float)acc[2]; res.w = (float)acc[3];
        ((float4*)out)[pi] = res;
    }
}

extern "C" void kernel_launch(void* const* d_in, const int* in_sizes, int n_in,
                              void* d_out, int out_size, void* d_ws, size_t ws_size,
                              hipStream_t stream) {
    const float* y = (const float*)d_in[0];
    const float* W = (const float*)d_in[1];
    const float* V = (const float*)d_in[2];
    float* out = (float*)d_out;
    int B = in_sizes[0] / 8;
    int block = 256;
    int grid = (B + block - 1) / block;
    rel_particle_kernel<<<grid, block, 0, stream>>>(y, W, V, out, B);
}